// Round 5
// baseline (156.705 us; speedup 1.0000x reference)
//
#include <hip/hip_runtime.h>

#define N_NODES 50000
#define N_EDGES 800000
#define SCAN_BLK 1024
#define SCAN_NBLK ((N_NODES + SCAN_BLK - 1) / SCAN_BLK)   // 49
#define HB 16                       // histogram blocks
#define CHUNK (N_EDGES / HB)        // 50000 edges per block (exact)
#define QN 12500                    // node-range quarter (4 * 12500 = 50000)

// ---------------------------------------------------------------------------
// node1: 64 nodes/block. Wave w computes output cols j0=8w..8w+7 for 64 nodes.
// Weight indices wave-uniform -> s_load; x staged in LDS (stride 132).
//   sh row = [ x@Wf.T+bf (32) | reg_emb (16) | dep_emb (16) ]
//   p1 = sh @ W1_l.T, r1 = sh @ W1_r.T
// ---------------------------------------------------------------------------
__global__ __launch_bounds__(256) void node1_kernel(
    const float* __restrict__ x, const int* __restrict__ reg_id,
    const int* __restrict__ dep_id,
    const float* __restrict__ W_feat, const float* __restrict__ b_feat,
    const float* __restrict__ reg_emb, const float* __restrict__ dep_emb,
    const float* __restrict__ W1_l, const float* __restrict__ W1_r,
    float* __restrict__ p1, float* __restrict__ r1)
{
    __shared__ float sx[64 * 132];
    __shared__ float sh[64 * 68];

    const int tid = threadIdx.x;
    const int node0 = blockIdx.x * 64;

    for (int i = tid; i < 64 * 32; i += 256) {
        int row = i >> 5, c4 = i & 31;
        float4 v = make_float4(0.f, 0.f, 0.f, 0.f);
        int n = node0 + row;
        if (n < N_NODES) v = *(const float4*)&x[n * 128 + c4 * 4];
        *(float4*)&sx[row * 132 + c4 * 4] = v;
    }
    for (int i = tid; i < 64 * 16; i += 256) {
        int r = i >> 4, f = i & 15;
        int n = node0 + r;
        if (n < N_NODES) {
            sh[r * 68 + 32 + f] = reg_emb[reg_id[n] * 16 + f];
            sh[r * 68 + 48 + f] = dep_emb[dep_id[n] * 16 + f];
        }
    }
    __syncthreads();

    const int nl = tid & 63;
    const int j0 = __builtin_amdgcn_readfirstlane((tid >> 6) * 8);

    {
        float acc[8];
        #pragma unroll
        for (int jj = 0; jj < 8; ++jj) acc[jj] = b_feat[j0 + jj];
        #pragma unroll 4
        for (int k = 0; k < 128; k += 4) {
            float4 xv = *(const float4*)&sx[nl * 132 + k];
            #pragma unroll
            for (int jj = 0; jj < 8; ++jj) {
                const float* wr = &W_feat[(j0 + jj) * 128 + k];
                acc[jj] += xv.x * wr[0] + xv.y * wr[1] + xv.z * wr[2] + xv.w * wr[3];
            }
        }
        #pragma unroll
        for (int jj = 0; jj < 8; ++jj) sh[nl * 68 + j0 + jj] = acc[jj];
    }
    __syncthreads();

    {
        const float* Wbase = (j0 < 16) ? (W1_l + j0 * 64) : (W1_r + (j0 - 16) * 64);
        float acc[8];
        #pragma unroll
        for (int jj = 0; jj < 8; ++jj) acc[jj] = 0.f;
        #pragma unroll 4
        for (int k = 0; k < 64; k += 4) {
            float4 hv = *(const float4*)&sh[nl * 68 + k];
            #pragma unroll
            for (int jj = 0; jj < 8; ++jj) {
                const float* wr = &Wbase[jj * 64 + k];
                acc[jj] += hv.x * wr[0] + hv.y * wr[1] + hv.z * wr[2] + hv.w * wr[3];
            }
        }
        int n = node0 + nl;
        if (n < N_NODES) {
            float* outp = (j0 < 16) ? (p1 + n * 16 + j0) : (r1 + n * 16 + (j0 - 16));
            *(float4*)outp       = make_float4(acc[0], acc[1], acc[2], acc[3]);
            *(float4*)(outp + 4) = make_float4(acc[4], acc[5], acc[6], acc[7]);
        }
    }
}

// ---------------------------------------------------------------------------
// hist_lds: LDS-privatized degree histogram, NO global atomics.
// Block b owns edges [b*CHUNK, (b+1)*CHUNK). Four passes over node-range
// quarters; LDS atomicAdd return = block-local rank (order within a
// (block,dst) group is arbitrary — mean is permutation-invariant).
// Flush counts to part[b][n] with plain coalesced stores.
// ---------------------------------------------------------------------------
__global__ __launch_bounds__(1024) void hist_lds_kernel(
    const int* __restrict__ ei, int* __restrict__ part, int* __restrict__ lrank)
{
    __shared__ int cnt[QN];   // 50 KB
    const int b  = blockIdx.x;
    const int e0 = b * CHUNK;
    for (int q = 0; q < 4; ++q) {
        const int lo = q * QN;
        for (int i = threadIdx.x; i < QN; i += 1024) cnt[i] = 0;
        __syncthreads();
        for (int i = threadIdx.x; i < CHUNK; i += 1024) {
            int d = ei[N_EDGES + e0 + i] - lo;
            if ((unsigned)d < (unsigned)QN)
                lrank[e0 + i] = atomicAdd(&cnt[d], 1);
        }
        __syncthreads();
        for (int i = threadIdx.x; i < QN; i += 1024)
            part[b * N_NODES + lo + i] = cnt[i];
        __syncthreads();
    }
}

// ---------------------------------------------------------------------------
// scan1: per node n — cross-block exclusive prefix bp[b][n] of part[b][n],
// total degree -> block-local exclusive scan into rowp (+ parts for scan2).
// ---------------------------------------------------------------------------
__global__ __launch_bounds__(SCAN_BLK) void scan1_kernel(
    const int* __restrict__ part, int* __restrict__ bp,
    int* __restrict__ rowp, int* __restrict__ parts)
{
    __shared__ int buf[2][SCAN_BLK];
    int t = threadIdx.x;
    int i = blockIdx.x * SCAN_BLK + t;
    int v = 0;
    if (i < N_NODES) {
        int s = 0;
        #pragma unroll
        for (int b = 0; b < HB; ++b) {
            bp[b * N_NODES + i] = s;
            s += part[b * N_NODES + i];
        }
        v = s;
    }
    int cur = 0;
    buf[0][t] = v;
    __syncthreads();
    for (int off = 1; off < SCAN_BLK; off <<= 1) {
        int nv = buf[cur][t] + ((t >= off) ? buf[cur][t - off] : 0);
        buf[cur ^ 1][t] = nv;
        cur ^= 1;
        __syncthreads();
    }
    int incl = buf[cur][t];
    if (i < N_NODES) rowp[i] = incl - v;
    if (t == SCAN_BLK - 1) parts[blockIdx.x] = incl;
}

__global__ void scan2_kernel(const int* __restrict__ parts, int* __restrict__ poff)
{
    int t = threadIdx.x;   // one wave
    int orig = (t < SCAN_NBLK) ? parts[t] : 0;
    int v = orig;
    #pragma unroll
    for (int off = 1; off < 64; off <<= 1) {
        int u = __shfl_up(v, off, 64);
        if (t >= off) v += u;
    }
    if (t < SCAN_NBLK) poff[t] = v - orig;
}

__global__ __launch_bounds__(SCAN_BLK) void scan3_kernel(
    int* __restrict__ rowp, const int* __restrict__ poff)
{
    int i = blockIdx.x * SCAN_BLK + threadIdx.x;
    if (i < N_NODES) rowp[i] += poff[blockIdx.x];
}

// ---------------------------------------------------------------------------
// fill (atomic-free): pos = rowp[d] + bp[block_of(e)][d] + lrank[e]
// ---------------------------------------------------------------------------
__global__ __launch_bounds__(256) void fill_kernel(
    const int* __restrict__ ei, const int* __restrict__ rowp,
    const int* __restrict__ bp, const int* __restrict__ lrank,
    int* __restrict__ csrc)
{
    int t = blockIdx.x * 256 + threadIdx.x;
    if (t < N_EDGES) {
        int d = ei[N_EDGES + t];
        int b = t / CHUNK;
        csrc[rowp[d] + bp[b * N_NODES + d] + lrank[t]] = ei[t];
    }
}

// ---------------------------------------------------------------------------
// gather1: one wave per node; 16 edge slots x float4; butterfly reduce;
// slot 0 applies mean + bias + residual + relu.
// ---------------------------------------------------------------------------
__global__ __launch_bounds__(256) void gather1_kernel(
    const int* __restrict__ rowp, const int* __restrict__ csrc,
    const float* __restrict__ p1, const float* __restrict__ r1,
    const float* __restrict__ b1_l, float* __restrict__ h1)
{
    int n = (blockIdx.x * 256 + threadIdx.x) >> 6;
    if (n >= N_NODES) return;
    int lane = threadIdx.x & 63;
    int slot = lane >> 2, f4 = lane & 3;
    int start = rowp[n];
    int end = (n + 1 < N_NODES) ? rowp[n + 1] : N_EDGES;

    float4 acc = make_float4(0.f, 0.f, 0.f, 0.f);
    for (int e0 = start; e0 < end; e0 += 16) {
        int e = e0 + slot;
        if (e < end) {
            float4 v = *(const float4*)&p1[csrc[e] * 16 + f4 * 4];
            acc.x += v.x; acc.y += v.y; acc.z += v.z; acc.w += v.w;
        }
    }
    #pragma unroll
    for (int off = 4; off <= 32; off <<= 1) {
        acc.x += __shfl_xor(acc.x, off, 64);
        acc.y += __shfl_xor(acc.y, off, 64);
        acc.z += __shfl_xor(acc.z, off, 64);
        acc.w += __shfl_xor(acc.w, off, 64);
    }
    if (slot == 0) {
        float inv = 1.0f / fmaxf((float)(end - start), 1.0f);
        float4 rv = *(const float4*)&r1[n * 16 + f4 * 4];
        float4 bv = *(const float4*)&b1_l[f4 * 4];
        float4 o;
        o.x = fmaxf(acc.x * inv + bv.x + rv.x, 0.f);
        o.y = fmaxf(acc.y * inv + bv.y + rv.y, 0.f);
        o.z = fmaxf(acc.z * inv + bv.z + rv.z, 0.f);
        o.w = fmaxf(acc.w * inv + bv.w + rv.w, 0.f);
        *(float4*)&h1[n * 16 + f4 * 4] = o;
    }
}

// ---------------------------------------------------------------------------
// gather2 + node2 + final, fused. One wave per node.
// ---------------------------------------------------------------------------
__global__ __launch_bounds__(256) void gather2_kernel(
    const int* __restrict__ rowp, const int* __restrict__ csrc,
    const float* __restrict__ h1,
    const float* __restrict__ W2_l, const float* __restrict__ b2_l,
    const float* __restrict__ W2_r, const float* __restrict__ W_lin,
    const float* __restrict__ b_lin, float* __restrict__ out)
{
    int n = (blockIdx.x * 256 + threadIdx.x) >> 6;
    if (n >= N_NODES) return;
    int lane = threadIdx.x & 63;
    int slot = lane >> 2, f4 = lane & 3;
    int start = rowp[n];
    int end = (n + 1 < N_NODES) ? rowp[n + 1] : N_EDGES;

    float4 acc = make_float4(0.f, 0.f, 0.f, 0.f);
    for (int e0 = start; e0 < end; e0 += 16) {
        int e = e0 + slot;
        if (e < end) {
            float4 v = *(const float4*)&h1[csrc[e] * 16 + f4 * 4];
            acc.x += v.x; acc.y += v.y; acc.z += v.z; acc.w += v.w;
        }
    }
    #pragma unroll
    for (int off = 4; off <= 32; off <<= 1) {
        acc.x += __shfl_xor(acc.x, off, 64);
        acc.y += __shfl_xor(acc.y, off, 64);
        acc.z += __shfl_xor(acc.z, off, 64);
        acc.w += __shfl_xor(acc.w, off, 64);
    }
    float inv = 1.0f / fmaxf((float)(end - start), 1.0f);
    float4 m2 = make_float4(acc.x * inv, acc.y * inv, acc.z * inv, acc.w * inv);
    float4 hn = *(const float4*)&h1[n * 16 + f4 * 4];

    int j0 = slot * 2;
    float4 wl0 = *(const float4*)&W2_l[j0 * 16 + f4 * 4];
    float4 wl1 = *(const float4*)&W2_l[(j0 + 1) * 16 + f4 * 4];
    float4 wr0 = *(const float4*)&W2_r[j0 * 16 + f4 * 4];
    float4 wr1 = *(const float4*)&W2_r[(j0 + 1) * 16 + f4 * 4];

    float pa = m2.x * wl0.x + m2.y * wl0.y + m2.z * wl0.z + m2.w * wl0.w
             + hn.x * wr0.x + hn.y * wr0.y + hn.z * wr0.z + hn.w * wr0.w;
    float pb = m2.x * wl1.x + m2.y * wl1.y + m2.z * wl1.z + m2.w * wl1.w
             + hn.x * wr1.x + hn.y * wr1.y + hn.z * wr1.z + hn.w * wr1.w;
    pa += __shfl_xor(pa, 1, 64); pa += __shfl_xor(pa, 2, 64);
    pb += __shfl_xor(pb, 1, 64); pb += __shfl_xor(pb, 2, 64);

    float h2a = fmaxf(pa + b2_l[j0], 0.f);
    float h2b = fmaxf(pb + b2_l[j0 + 1], 0.f);
    float w = h2a * W_lin[j0] + h2b * W_lin[j0 + 1];
    #pragma unroll
    for (int off = 4; off <= 32; off <<= 1) w += __shfl_xor(w, off, 64);
    if (lane == 0) out[n] = w + b_lin[0];
}

extern "C" void kernel_launch(void* const* d_in, const int* in_sizes, int n_in,
                              void* d_out, int out_size, void* d_ws, size_t ws_size,
                              hipStream_t stream) {
    const float* x       = (const float*)d_in[0];
    const int*   ei      = (const int*)  d_in[1];
    const int*   reg_id  = (const int*)  d_in[2];
    const int*   dep_id  = (const int*)  d_in[3];
    const float* W_feat  = (const float*)d_in[4];
    const float* b_feat  = (const float*)d_in[5];
    const float* reg_emb = (const float*)d_in[6];
    const float* dep_emb = (const float*)d_in[7];
    const float* W1_l    = (const float*)d_in[8];
    const float* b1_l    = (const float*)d_in[9];
    const float* W1_r    = (const float*)d_in[10];
    const float* W2_l    = (const float*)d_in[11];
    const float* b2_l    = (const float*)d_in[12];
    const float* W2_r    = (const float*)d_in[13];
    const float* W_lin   = (const float*)d_in[14];
    const float* b_lin   = (const float*)d_in[15];
    float* out = (float*)d_out;
    float* ws  = (float*)d_ws;

    const int N = N_NODES;
    // workspace (every word fully written each call — no memset needed)
    float* p1 = ws;                          // [N,16]
    float* r1 = ws + 16 * N;                 // [N,16]
    float* h1 = ws + 32 * N;                 // [N,16]
    int* part  = (int*)(ws + 48 * N);        // [HB,N]
    int* bp    = part + HB * N;              // [HB,N]
    int* rowp  = bp + HB * N;                // [N]
    int* lrank = rowp + N;                   // [E]
    int* csrc  = lrank + N_EDGES;            // [E]
    int* parts = csrc + N_EDGES;             // [64]
    int* poff  = parts + 64;                 // [64]
    // total: 48N + 33N + 2E + 128 ints/floats ≈ 22.6 MB

    node1_kernel<<<(N + 63) / 64, 256, 0, stream>>>(
        x, reg_id, dep_id, W_feat, b_feat, reg_emb, dep_emb, W1_l, W1_r, p1, r1);

    hist_lds_kernel<<<HB, 1024, 0, stream>>>(ei, part, lrank);
    scan1_kernel<<<SCAN_NBLK, SCAN_BLK, 0, stream>>>(part, bp, rowp, parts);
    scan2_kernel<<<1, 64, 0, stream>>>(parts, poff);
    scan3_kernel<<<SCAN_NBLK, SCAN_BLK, 0, stream>>>(rowp, poff);
    fill_kernel<<<(N_EDGES + 255) / 256, 256, 0, stream>>>(ei, rowp, bp, lrank, csrc);

    gather1_kernel<<<(N * 64 + 255) / 256, 256, 0, stream>>>(
        rowp, csrc, p1, r1, b1_l, h1);

    gather2_kernel<<<(N * 64 + 255) / 256, 256, 0, stream>>>(
        rowp, csrc, h1, W2_l, b2_l, W2_r, W_lin, b_lin, out);
}

// Round 6
// 121.880 us; speedup vs baseline: 1.2857x; 1.2857x over previous
//
#include <hip/hip_runtime.h>

#define N_NODES 50000
#define N_EDGES 800000
#define SCAN_BLK 1024
#define SCAN_NBLK ((N_NODES + SCAN_BLK - 1) / SCAN_BLK)   // 49
#define HB 64                       // histogram blocks (1 CU each)
#define CHUNK (N_EDGES / HB)        // 12500 edges per block (exact)
#define QN 12500                    // node-range quarter (4 * 12500 = 50000)
#define EPT ((CHUNK + 1023) / 1024) // 13 edges per thread (registers)

// ---------------------------------------------------------------------------
// node1: 64 nodes/block. Wave w computes output cols j0=8w..8w+7 for 64 nodes.
// Weight indices wave-uniform -> s_load; x staged in LDS (stride 132).
//   sh row = [ x@Wf.T+bf (32) | reg_emb (16) | dep_emb (16) ]
//   p1 = sh @ W1_l.T, r1 = sh @ W1_r.T
// ---------------------------------------------------------------------------
__global__ __launch_bounds__(256) void node1_kernel(
    const float* __restrict__ x, const int* __restrict__ reg_id,
    const int* __restrict__ dep_id,
    const float* __restrict__ W_feat, const float* __restrict__ b_feat,
    const float* __restrict__ reg_emb, const float* __restrict__ dep_emb,
    const float* __restrict__ W1_l, const float* __restrict__ W1_r,
    float* __restrict__ p1, float* __restrict__ r1)
{
    __shared__ float sx[64 * 132];
    __shared__ float sh[64 * 68];

    const int tid = threadIdx.x;
    const int node0 = blockIdx.x * 64;

    for (int i = tid; i < 64 * 32; i += 256) {
        int row = i >> 5, c4 = i & 31;
        float4 v = make_float4(0.f, 0.f, 0.f, 0.f);
        int n = node0 + row;
        if (n < N_NODES) v = *(const float4*)&x[n * 128 + c4 * 4];
        *(float4*)&sx[row * 132 + c4 * 4] = v;
    }
    for (int i = tid; i < 64 * 16; i += 256) {
        int r = i >> 4, f = i & 15;
        int n = node0 + r;
        if (n < N_NODES) {
            sh[r * 68 + 32 + f] = reg_emb[reg_id[n] * 16 + f];
            sh[r * 68 + 48 + f] = dep_emb[dep_id[n] * 16 + f];
        }
    }
    __syncthreads();

    const int nl = tid & 63;
    const int j0 = __builtin_amdgcn_readfirstlane((tid >> 6) * 8);

    {
        float acc[8];
        #pragma unroll
        for (int jj = 0; jj < 8; ++jj) acc[jj] = b_feat[j0 + jj];
        #pragma unroll 4
        for (int k = 0; k < 128; k += 4) {
            float4 xv = *(const float4*)&sx[nl * 132 + k];
            #pragma unroll
            for (int jj = 0; jj < 8; ++jj) {
                const float* wr = &W_feat[(j0 + jj) * 128 + k];
                acc[jj] += xv.x * wr[0] + xv.y * wr[1] + xv.z * wr[2] + xv.w * wr[3];
            }
        }
        #pragma unroll
        for (int jj = 0; jj < 8; ++jj) sh[nl * 68 + j0 + jj] = acc[jj];
    }
    __syncthreads();

    {
        const float* Wbase = (j0 < 16) ? (W1_l + j0 * 64) : (W1_r + (j0 - 16) * 64);
        float acc[8];
        #pragma unroll
        for (int jj = 0; jj < 8; ++jj) acc[jj] = 0.f;
        #pragma unroll 4
        for (int k = 0; k < 64; k += 4) {
            float4 hv = *(const float4*)&sh[nl * 68 + k];
            #pragma unroll
            for (int jj = 0; jj < 8; ++jj) {
                const float* wr = &Wbase[jj * 64 + k];
                acc[jj] += hv.x * wr[0] + hv.y * wr[1] + hv.z * wr[2] + hv.w * wr[3];
            }
        }
        int n = node0 + nl;
        if (n < N_NODES) {
            float* outp = (j0 < 16) ? (p1 + n * 16 + j0) : (r1 + n * 16 + (j0 - 16));
            *(float4*)outp       = make_float4(acc[0], acc[1], acc[2], acc[3]);
            *(float4*)(outp + 4) = make_float4(acc[4], acc[5], acc[6], acc[7]);
        }
    }
}

// ---------------------------------------------------------------------------
// hist_lds: LDS-privatized degree histogram, NO global atomics.
// 64 blocks x 1024 threads; block b owns edges [b*CHUNK,(b+1)*CHUNK).
// dst values pre-loaded to registers ONCE; 4 node-range quarter passes do
// only {LDS atomic, lrank store}. LDS atomic return = block-local rank
// (order within a (block,dst) group arbitrary — mean is perm-invariant).
// Counts flushed to part[b][n] with plain coalesced stores.
// ---------------------------------------------------------------------------
__global__ __launch_bounds__(1024) void hist_lds_kernel(
    const int* __restrict__ ei, int* __restrict__ part, int* __restrict__ lrank)
{
    __shared__ int cnt[QN];   // 50 KB
    const int b  = blockIdx.x;
    const int e0 = b * CHUNK;

    int dv[EPT];
    #pragma unroll
    for (int k = 0; k < EPT; ++k) {
        int i = threadIdx.x + k * 1024;
        dv[k] = (i < CHUNK) ? ei[N_EDGES + e0 + i] : -1;
    }

    for (int q = 0; q < 4; ++q) {
        const int lo = q * QN;
        for (int i = threadIdx.x; i < QN; i += 1024) cnt[i] = 0;
        __syncthreads();
        #pragma unroll
        for (int k = 0; k < EPT; ++k) {
            int d = dv[k] - lo;
            if ((unsigned)d < (unsigned)QN)
                lrank[e0 + threadIdx.x + k * 1024] = atomicAdd(&cnt[d], 1);
        }
        __syncthreads();
        for (int i = threadIdx.x; i < QN; i += 1024)
            part[b * N_NODES + lo + i] = cnt[i];
        __syncthreads();
    }
}

// ---------------------------------------------------------------------------
// scan1: per node i — convert part[b][i] to cross-block exclusive prefix
// IN-PLACE; total degree -> block-local exclusive scan into rowp1
// (+ per-block totals for scan2).
// ---------------------------------------------------------------------------
__global__ __launch_bounds__(SCAN_BLK) void scan1_kernel(
    int* __restrict__ part, int* __restrict__ rowp1, int* __restrict__ parts)
{
    __shared__ int buf[2][SCAN_BLK];
    int t = threadIdx.x;
    int i = blockIdx.x * SCAN_BLK + t;
    int v = 0;
    if (i < N_NODES) {
        int s = 0;
        #pragma unroll
        for (int b = 0; b < HB; ++b) {
            int c = part[b * N_NODES + i];
            part[b * N_NODES + i] = s;
            s += c;
        }
        v = s;
    }
    int cur = 0;
    buf[0][t] = v;
    __syncthreads();
    for (int off = 1; off < SCAN_BLK; off <<= 1) {
        int nv = buf[cur][t] + ((t >= off) ? buf[cur][t - off] : 0);
        buf[cur ^ 1][t] = nv;
        cur ^= 1;
        __syncthreads();
    }
    int incl = buf[cur][t];
    if (i < N_NODES) rowp1[i] = incl - v;          // block-local exclusive
    if (t == SCAN_BLK - 1) parts[blockIdx.x] = incl;
}

__global__ void scan2_kernel(const int* __restrict__ parts, int* __restrict__ poff)
{
    int t = threadIdx.x;   // one wave
    int orig = (t < SCAN_NBLK) ? parts[t] : 0;
    int v = orig;
    #pragma unroll
    for (int off = 1; off < 64; off <<= 1) {
        int u = __shfl_up(v, off, 64);
        if (t >= off) v += u;
    }
    if (t < SCAN_NBLK) poff[t] = v - orig;
}

// ---------------------------------------------------------------------------
// fill (atomic-free): pos = rowp(d) + bp[block_of(e)][d] + lrank[e]
// where rowp(d) = rowp1[d] + poff[d>>10]  (scan3 folded in)
// ---------------------------------------------------------------------------
__global__ __launch_bounds__(256) void fill_kernel(
    const int* __restrict__ ei, const int* __restrict__ rowp1,
    const int* __restrict__ poff, const int* __restrict__ bp,
    const int* __restrict__ lrank, int* __restrict__ csrc)
{
    int t = blockIdx.x * 256 + threadIdx.x;
    if (t < N_EDGES) {
        int d = ei[N_EDGES + t];
        int b = t / CHUNK;
        int pos = rowp1[d] + poff[d >> 10] + bp[b * N_NODES + d] + lrank[t];
        csrc[pos] = ei[t];
    }
}

// ---------------------------------------------------------------------------
// gather1: one wave per node; 16 edge slots x float4; butterfly reduce;
// slot 0 applies mean + bias + residual + relu.
// ---------------------------------------------------------------------------
__global__ __launch_bounds__(256) void gather1_kernel(
    const int* __restrict__ rowp1, const int* __restrict__ poff,
    const int* __restrict__ csrc,
    const float* __restrict__ p1, const float* __restrict__ r1,
    const float* __restrict__ b1_l, float* __restrict__ h1)
{
    int n = (blockIdx.x * 256 + threadIdx.x) >> 6;
    if (n >= N_NODES) return;
    int lane = threadIdx.x & 63;
    int slot = lane >> 2, f4 = lane & 3;
    int start = rowp1[n] + poff[n >> 10];
    int end = (n + 1 < N_NODES) ? rowp1[n + 1] + poff[(n + 1) >> 10] : N_EDGES;

    float4 acc = make_float4(0.f, 0.f, 0.f, 0.f);
    for (int e0 = start; e0 < end; e0 += 16) {
        int e = e0 + slot;
        if (e < end) {
            float4 v = *(const float4*)&p1[csrc[e] * 16 + f4 * 4];
            acc.x += v.x; acc.y += v.y; acc.z += v.z; acc.w += v.w;
        }
    }
    #pragma unroll
    for (int off = 4; off <= 32; off <<= 1) {
        acc.x += __shfl_xor(acc.x, off, 64);
        acc.y += __shfl_xor(acc.y, off, 64);
        acc.z += __shfl_xor(acc.z, off, 64);
        acc.w += __shfl_xor(acc.w, off, 64);
    }
    if (slot == 0) {
        float inv = 1.0f / fmaxf((float)(end - start), 1.0f);
        float4 rv = *(const float4*)&r1[n * 16 + f4 * 4];
        float4 bv = *(const float4*)&b1_l[f4 * 4];
        float4 o;
        o.x = fmaxf(acc.x * inv + bv.x + rv.x, 0.f);
        o.y = fmaxf(acc.y * inv + bv.y + rv.y, 0.f);
        o.z = fmaxf(acc.z * inv + bv.z + rv.z, 0.f);
        o.w = fmaxf(acc.w * inv + bv.w + rv.w, 0.f);
        *(float4*)&h1[n * 16 + f4 * 4] = o;
    }
}

// ---------------------------------------------------------------------------
// gather2 + node2 + final, fused. One wave per node.
// ---------------------------------------------------------------------------
__global__ __launch_bounds__(256) void gather2_kernel(
    const int* __restrict__ rowp1, const int* __restrict__ poff,
    const int* __restrict__ csrc, const float* __restrict__ h1,
    const float* __restrict__ W2_l, const float* __restrict__ b2_l,
    const float* __restrict__ W2_r, const float* __restrict__ W_lin,
    const float* __restrict__ b_lin, float* __restrict__ out)
{
    int n = (blockIdx.x * 256 + threadIdx.x) >> 6;
    if (n >= N_NODES) return;
    int lane = threadIdx.x & 63;
    int slot = lane >> 2, f4 = lane & 3;
    int start = rowp1[n] + poff[n >> 10];
    int end = (n + 1 < N_NODES) ? rowp1[n + 1] + poff[(n + 1) >> 10] : N_EDGES;

    float4 acc = make_float4(0.f, 0.f, 0.f, 0.f);
    for (int e0 = start; e0 < end; e0 += 16) {
        int e = e0 + slot;
        if (e < end) {
            float4 v = *(const float4*)&h1[csrc[e] * 16 + f4 * 4];
            acc.x += v.x; acc.y += v.y; acc.z += v.z; acc.w += v.w;
        }
    }
    #pragma unroll
    for (int off = 4; off <= 32; off <<= 1) {
        acc.x += __shfl_xor(acc.x, off, 64);
        acc.y += __shfl_xor(acc.y, off, 64);
        acc.z += __shfl_xor(acc.z, off, 64);
        acc.w += __shfl_xor(acc.w, off, 64);
    }
    float inv = 1.0f / fmaxf((float)(end - start), 1.0f);
    float4 m2 = make_float4(acc.x * inv, acc.y * inv, acc.z * inv, acc.w * inv);
    float4 hn = *(const float4*)&h1[n * 16 + f4 * 4];

    int j0 = slot * 2;
    float4 wl0 = *(const float4*)&W2_l[j0 * 16 + f4 * 4];
    float4 wl1 = *(const float4*)&W2_l[(j0 + 1) * 16 + f4 * 4];
    float4 wr0 = *(const float4*)&W2_r[j0 * 16 + f4 * 4];
    float4 wr1 = *(const float4*)&W2_r[(j0 + 1) * 16 + f4 * 4];

    float pa = m2.x * wl0.x + m2.y * wl0.y + m2.z * wl0.z + m2.w * wl0.w
             + hn.x * wr0.x + hn.y * wr0.y + hn.z * wr0.z + hn.w * wr0.w;
    float pb = m2.x * wl1.x + m2.y * wl1.y + m2.z * wl1.z + m2.w * wl1.w
             + hn.x * wr1.x + hn.y * wr1.y + hn.z * wr1.z + hn.w * wr1.w;
    pa += __shfl_xor(pa, 1, 64); pa += __shfl_xor(pa, 2, 64);
    pb += __shfl_xor(pb, 1, 64); pb += __shfl_xor(pb, 2, 64);

    float h2a = fmaxf(pa + b2_l[j0], 0.f);
    float h2b = fmaxf(pb + b2_l[j0 + 1], 0.f);
    float w = h2a * W_lin[j0] + h2b * W_lin[j0 + 1];
    #pragma unroll
    for (int off = 4; off <= 32; off <<= 1) w += __shfl_xor(w, off, 64);
    if (lane == 0) out[n] = w + b_lin[0];
}

extern "C" void kernel_launch(void* const* d_in, const int* in_sizes, int n_in,
                              void* d_out, int out_size, void* d_ws, size_t ws_size,
                              hipStream_t stream) {
    const float* x       = (const float*)d_in[0];
    const int*   ei      = (const int*)  d_in[1];
    const int*   reg_id  = (const int*)  d_in[2];
    const int*   dep_id  = (const int*)  d_in[3];
    const float* W_feat  = (const float*)d_in[4];
    const float* b_feat  = (const float*)d_in[5];
    const float* reg_emb = (const float*)d_in[6];
    const float* dep_emb = (const float*)d_in[7];
    const float* W1_l    = (const float*)d_in[8];
    const float* b1_l    = (const float*)d_in[9];
    const float* W1_r    = (const float*)d_in[10];
    const float* W2_l    = (const float*)d_in[11];
    const float* b2_l    = (const float*)d_in[12];
    const float* W2_r    = (const float*)d_in[13];
    const float* W_lin   = (const float*)d_in[14];
    const float* b_lin   = (const float*)d_in[15];
    float* out = (float*)d_out;
    float* ws  = (float*)d_ws;

    const int N = N_NODES;
    // workspace (every word fully written each call — no memset needed)
    float* p1 = ws;                          // [N,16]
    float* r1 = ws + 16 * N;                 // [N,16]
    float* h1 = ws + 32 * N;                 // [N,16]
    int* part  = (int*)(ws + 48 * N);        // [HB,N] counts -> bp in-place
    int* rowp1 = part + HB * N;              // [N]
    int* lrank = rowp1 + N;                  // [E]
    int* csrc  = lrank + N_EDGES;            // [E]
    int* parts = csrc + N_EDGES;             // [64]
    int* poff  = parts + 64;                 // [64]
    // total: (48 + 65)N + 2E + 128 words ≈ 29 MB

    node1_kernel<<<(N + 63) / 64, 256, 0, stream>>>(
        x, reg_id, dep_id, W_feat, b_feat, reg_emb, dep_emb, W1_l, W1_r, p1, r1);

    hist_lds_kernel<<<HB, 1024, 0, stream>>>(ei, part, lrank);
    scan1_kernel<<<SCAN_NBLK, SCAN_BLK, 0, stream>>>(part, rowp1, parts);
    scan2_kernel<<<1, 64, 0, stream>>>(parts, poff);
    fill_kernel<<<(N_EDGES + 255) / 256, 256, 0, stream>>>(
        ei, rowp1, poff, part, lrank, csrc);

    gather1_kernel<<<(N * 64 + 255) / 256, 256, 0, stream>>>(
        rowp1, poff, csrc, p1, r1, b1_l, h1);

    gather2_kernel<<<(N * 64 + 255) / 256, 256, 0, stream>>>(
        rowp1, poff, csrc, h1, W2_l, b2_l, W2_r, W_lin, b_lin, out);
}

// Round 7
// 115.671 us; speedup vs baseline: 1.3547x; 1.0537x over previous
//
#include <hip/hip_runtime.h>

#define N_NODES 50000
#define N_EDGES 800000
#define SCAN_BLK 1024
#define SCAN_NBLK ((N_NODES + SCAN_BLK - 1) / SCAN_BLK)   // 49
#define HB 64                       // histogram blocks
#define CHUNK (N_EDGES / HB)        // 12500 edges per block (exact)
#define EPT ((CHUNK + 1023) / 1024) // 13 edges per thread
#define CNTW (N_NODES / 4)          // 12500 packed u32 = 50 KB LDS

// ---------------------------------------------------------------------------
// node1: 64 nodes/block. Wave w computes output cols j0=8w..8w+7 for 64 nodes.
// Weight indices wave-uniform -> s_load; x staged in LDS (stride 132).
//   sh row = [ x@Wf.T+bf (32) | reg_emb (16) | dep_emb (16) ]
//   p1 = sh @ W1_l.T, r1 = sh @ W1_r.T
// ---------------------------------------------------------------------------
__global__ __launch_bounds__(256) void node1_kernel(
    const float* __restrict__ x, const int* __restrict__ reg_id,
    const int* __restrict__ dep_id,
    const float* __restrict__ W_feat, const float* __restrict__ b_feat,
    const float* __restrict__ reg_emb, const float* __restrict__ dep_emb,
    const float* __restrict__ W1_l, const float* __restrict__ W1_r,
    float* __restrict__ p1, float* __restrict__ r1)
{
    __shared__ float sx[64 * 132];
    __shared__ float sh[64 * 68];

    const int tid = threadIdx.x;
    const int node0 = blockIdx.x * 64;

    for (int i = tid; i < 64 * 32; i += 256) {
        int row = i >> 5, c4 = i & 31;
        float4 v = make_float4(0.f, 0.f, 0.f, 0.f);
        int n = node0 + row;
        if (n < N_NODES) v = *(const float4*)&x[n * 128 + c4 * 4];
        *(float4*)&sx[row * 132 + c4 * 4] = v;
    }
    for (int i = tid; i < 64 * 16; i += 256) {
        int r = i >> 4, f = i & 15;
        int n = node0 + r;
        if (n < N_NODES) {
            sh[r * 68 + 32 + f] = reg_emb[reg_id[n] * 16 + f];
            sh[r * 68 + 48 + f] = dep_emb[dep_id[n] * 16 + f];
        }
    }
    __syncthreads();

    const int nl = tid & 63;
    const int j0 = __builtin_amdgcn_readfirstlane((tid >> 6) * 8);

    {
        float acc[8];
        #pragma unroll
        for (int jj = 0; jj < 8; ++jj) acc[jj] = b_feat[j0 + jj];
        #pragma unroll 4
        for (int k = 0; k < 128; k += 4) {
            float4 xv = *(const float4*)&sx[nl * 132 + k];
            #pragma unroll
            for (int jj = 0; jj < 8; ++jj) {
                const float* wr = &W_feat[(j0 + jj) * 128 + k];
                acc[jj] += xv.x * wr[0] + xv.y * wr[1] + xv.z * wr[2] + xv.w * wr[3];
            }
        }
        #pragma unroll
        for (int jj = 0; jj < 8; ++jj) sh[nl * 68 + j0 + jj] = acc[jj];
    }
    __syncthreads();

    {
        const float* Wbase = (j0 < 16) ? (W1_l + j0 * 64) : (W1_r + (j0 - 16) * 64);
        float acc[8];
        #pragma unroll
        for (int jj = 0; jj < 8; ++jj) acc[jj] = 0.f;
        #pragma unroll 4
        for (int k = 0; k < 64; k += 4) {
            float4 hv = *(const float4*)&sh[nl * 68 + k];
            #pragma unroll
            for (int jj = 0; jj < 8; ++jj) {
                const float* wr = &Wbase[jj * 64 + k];
                acc[jj] += hv.x * wr[0] + hv.y * wr[1] + hv.z * wr[2] + hv.w * wr[3];
            }
        }
        int n = node0 + nl;
        if (n < N_NODES) {
            float* outp = (j0 < 16) ? (p1 + n * 16 + j0) : (r1 + n * 16 + (j0 - 16));
            *(float4*)outp       = make_float4(acc[0], acc[1], acc[2], acc[3]);
            *(float4*)(outp + 4) = make_float4(acc[4], acc[5], acc[6], acc[7]);
        }
    }
}

// ---------------------------------------------------------------------------
// hist_lds: single-pass LDS histogram, packed 8-bit counters (4 nodes/u32),
// NO global atomics. Per-(block,node) count <= ~6 << 255, so no byte carry.
// Atomic return byte = block-local rank (order within (block,dst) arbitrary —
// mean is permutation-invariant). part stored PACKED (u32, 4 counts).
// ---------------------------------------------------------------------------
__global__ __launch_bounds__(1024) void hist_lds_kernel(
    const int* __restrict__ ei, unsigned int* __restrict__ part,
    int* __restrict__ lrank)
{
    __shared__ unsigned int cnt[CNTW];   // 50 KB
    const int b  = blockIdx.x;
    const int e0 = b * CHUNK;

    for (int i = threadIdx.x; i < CNTW; i += 1024) cnt[i] = 0u;
    __syncthreads();

    #pragma unroll
    for (int k = 0; k < EPT; ++k) {
        int i = threadIdx.x + k * 1024;
        if (i < CHUNK) {
            int d = ei[N_EDGES + e0 + i];
            unsigned sh = (unsigned)(d & 3) * 8u;
            unsigned old = atomicAdd(&cnt[d >> 2], 1u << sh);
            lrank[e0 + i] = (int)((old >> sh) & 0xffu);
        }
    }
    __syncthreads();

    for (int i = threadIdx.x; i < CNTW; i += 1024)
        part[b * CNTW + i] = cnt[i];
}

// ---------------------------------------------------------------------------
// scan1: per node i — unpack part bytes, build cross-block exclusive prefix
// bp[b][i] (int), total degree -> block-local exclusive scan into rowp1
// (+ per-block totals for scan2).
// ---------------------------------------------------------------------------
__global__ __launch_bounds__(SCAN_BLK) void scan1_kernel(
    const unsigned int* __restrict__ part, int* __restrict__ bp,
    int* __restrict__ rowp1, int* __restrict__ parts)
{
    __shared__ int buf[2][SCAN_BLK];
    int t = threadIdx.x;
    int i = blockIdx.x * SCAN_BLK + t;
    int v = 0;
    if (i < N_NODES) {
        int w = i >> 2;
        unsigned sh = (unsigned)(i & 3) * 8u;
        int s = 0;
        #pragma unroll
        for (int b = 0; b < HB; ++b) {
            bp[b * N_NODES + i] = s;
            s += (int)((part[b * CNTW + w] >> sh) & 0xffu);
        }
        v = s;
    }
    int cur = 0;
    buf[0][t] = v;
    __syncthreads();
    for (int off = 1; off < SCAN_BLK; off <<= 1) {
        int nv = buf[cur][t] + ((t >= off) ? buf[cur][t - off] : 0);
        buf[cur ^ 1][t] = nv;
        cur ^= 1;
        __syncthreads();
    }
    int incl = buf[cur][t];
    if (i < N_NODES) rowp1[i] = incl - v;          // block-local exclusive
    if (t == SCAN_BLK - 1) parts[blockIdx.x] = incl;
}

__global__ void scan2_kernel(const int* __restrict__ parts, int* __restrict__ poff)
{
    int t = threadIdx.x;   // one wave
    int orig = (t < SCAN_NBLK) ? parts[t] : 0;
    int v = orig;
    #pragma unroll
    for (int off = 1; off < 64; off <<= 1) {
        int u = __shfl_up(v, off, 64);
        if (t >= off) v += u;
    }
    if (t < SCAN_NBLK) poff[t] = v - orig;
}

// ---------------------------------------------------------------------------
// fill (atomic-free): pos = rowp(d) + bp[block_of(e)][d] + lrank[e]
// where rowp(d) = rowp1[d] + poff[d>>10]  (scan3 folded in)
// ---------------------------------------------------------------------------
__global__ __launch_bounds__(256) void fill_kernel(
    const int* __restrict__ ei, const int* __restrict__ rowp1,
    const int* __restrict__ poff, const int* __restrict__ bp,
    const int* __restrict__ lrank, int* __restrict__ csrc)
{
    int t = blockIdx.x * 256 + threadIdx.x;
    if (t < N_EDGES) {
        int d = ei[N_EDGES + t];
        int b = t / CHUNK;
        int pos = rowp1[d] + poff[d >> 10] + bp[b * N_NODES + d] + lrank[t];
        csrc[pos] = ei[t];
    }
}

// ---------------------------------------------------------------------------
// gather1: one wave per node; 16 edge slots x float4; butterfly reduce;
// slot 0 applies mean + bias + residual + relu.
// ---------------------------------------------------------------------------
__global__ __launch_bounds__(256) void gather1_kernel(
    const int* __restrict__ rowp1, const int* __restrict__ poff,
    const int* __restrict__ csrc,
    const float* __restrict__ p1, const float* __restrict__ r1,
    const float* __restrict__ b1_l, float* __restrict__ h1)
{
    int n = (blockIdx.x * 256 + threadIdx.x) >> 6;
    if (n >= N_NODES) return;
    int lane = threadIdx.x & 63;
    int slot = lane >> 2, f4 = lane & 3;
    int start = rowp1[n] + poff[n >> 10];
    int end = (n + 1 < N_NODES) ? rowp1[n + 1] + poff[(n + 1) >> 10] : N_EDGES;

    float4 acc = make_float4(0.f, 0.f, 0.f, 0.f);
    for (int e0 = start; e0 < end; e0 += 16) {
        int e = e0 + slot;
        if (e < end) {
            float4 v = *(const float4*)&p1[csrc[e] * 16 + f4 * 4];
            acc.x += v.x; acc.y += v.y; acc.z += v.z; acc.w += v.w;
        }
    }
    #pragma unroll
    for (int off = 4; off <= 32; off <<= 1) {
        acc.x += __shfl_xor(acc.x, off, 64);
        acc.y += __shfl_xor(acc.y, off, 64);
        acc.z += __shfl_xor(acc.z, off, 64);
        acc.w += __shfl_xor(acc.w, off, 64);
    }
    if (slot == 0) {
        float inv = 1.0f / fmaxf((float)(end - start), 1.0f);
        float4 rv = *(const float4*)&r1[n * 16 + f4 * 4];
        float4 bv = *(const float4*)&b1_l[f4 * 4];
        float4 o;
        o.x = fmaxf(acc.x * inv + bv.x + rv.x, 0.f);
        o.y = fmaxf(acc.y * inv + bv.y + rv.y, 0.f);
        o.z = fmaxf(acc.z * inv + bv.z + rv.z, 0.f);
        o.w = fmaxf(acc.w * inv + bv.w + rv.w, 0.f);
        *(float4*)&h1[n * 16 + f4 * 4] = o;
    }
}

// ---------------------------------------------------------------------------
// gather2 + node2 + final, fused. One wave per node.
// ---------------------------------------------------------------------------
__global__ __launch_bounds__(256) void gather2_kernel(
    const int* __restrict__ rowp1, const int* __restrict__ poff,
    const int* __restrict__ csrc, const float* __restrict__ h1,
    const float* __restrict__ W2_l, const float* __restrict__ b2_l,
    const float* __restrict__ W2_r, const float* __restrict__ W_lin,
    const float* __restrict__ b_lin, float* __restrict__ out)
{
    int n = (blockIdx.x * 256 + threadIdx.x) >> 6;
    if (n >= N_NODES) return;
    int lane = threadIdx.x & 63;
    int slot = lane >> 2, f4 = lane & 3;
    int start = rowp1[n] + poff[n >> 10];
    int end = (n + 1 < N_NODES) ? rowp1[n + 1] + poff[(n + 1) >> 10] : N_EDGES;

    float4 acc = make_float4(0.f, 0.f, 0.f, 0.f);
    for (int e0 = start; e0 < end; e0 += 16) {
        int e = e0 + slot;
        if (e < end) {
            float4 v = *(const float4*)&h1[csrc[e] * 16 + f4 * 4];
            acc.x += v.x; acc.y += v.y; acc.z += v.z; acc.w += v.w;
        }
    }
    #pragma unroll
    for (int off = 4; off <= 32; off <<= 1) {
        acc.x += __shfl_xor(acc.x, off, 64);
        acc.y += __shfl_xor(acc.y, off, 64);
        acc.z += __shfl_xor(acc.z, off, 64);
        acc.w += __shfl_xor(acc.w, off, 64);
    }
    float inv = 1.0f / fmaxf((float)(end - start), 1.0f);
    float4 m2 = make_float4(acc.x * inv, acc.y * inv, acc.z * inv, acc.w * inv);
    float4 hn = *(const float4*)&h1[n * 16 + f4 * 4];

    int j0 = slot * 2;
    float4 wl0 = *(const float4*)&W2_l[j0 * 16 + f4 * 4];
    float4 wl1 = *(const float4*)&W2_l[(j0 + 1) * 16 + f4 * 4];
    float4 wr0 = *(const float4*)&W2_r[j0 * 16 + f4 * 4];
    float4 wr1 = *(const float4*)&W2_r[(j0 + 1) * 16 + f4 * 4];

    float pa = m2.x * wl0.x + m2.y * wl0.y + m2.z * wl0.z + m2.w * wl0.w
             + hn.x * wr0.x + hn.y * wr0.y + hn.z * wr0.z + hn.w * wr0.w;
    float pb = m2.x * wl1.x + m2.y * wl1.y + m2.z * wl1.z + m2.w * wl1.w
             + hn.x * wr1.x + hn.y * wr1.y + hn.z * wr1.z + hn.w * wr1.w;
    pa += __shfl_xor(pa, 1, 64); pa += __shfl_xor(pa, 2, 64);
    pb += __shfl_xor(pb, 1, 64); pb += __shfl_xor(pb, 2, 64);

    float h2a = fmaxf(pa + b2_l[j0], 0.f);
    float h2b = fmaxf(pb + b2_l[j0 + 1], 0.f);
    float w = h2a * W_lin[j0] + h2b * W_lin[j0 + 1];
    #pragma unroll
    for (int off = 4; off <= 32; off <<= 1) w += __shfl_xor(w, off, 64);
    if (lane == 0) out[n] = w + b_lin[0];
}

extern "C" void kernel_launch(void* const* d_in, const int* in_sizes, int n_in,
                              void* d_out, int out_size, void* d_ws, size_t ws_size,
                              hipStream_t stream) {
    const float* x       = (const float*)d_in[0];
    const int*   ei      = (const int*)  d_in[1];
    const int*   reg_id  = (const int*)  d_in[2];
    const int*   dep_id  = (const int*)  d_in[3];
    const float* W_feat  = (const float*)d_in[4];
    const float* b_feat  = (const float*)d_in[5];
    const float* reg_emb = (const float*)d_in[6];
    const float* dep_emb = (const float*)d_in[7];
    const float* W1_l    = (const float*)d_in[8];
    const float* b1_l    = (const float*)d_in[9];
    const float* W1_r    = (const float*)d_in[10];
    const float* W2_l    = (const float*)d_in[11];
    const float* b2_l    = (const float*)d_in[12];
    const float* W2_r    = (const float*)d_in[13];
    const float* W_lin   = (const float*)d_in[14];
    const float* b_lin   = (const float*)d_in[15];
    float* out = (float*)d_out;
    float* ws  = (float*)d_ws;

    const int N = N_NODES;
    // workspace (every word fully written each call — no memset needed)
    float* p1 = ws;                              // [N,16]
    float* r1 = ws + 16 * N;                     // [N,16]
    float* h1 = ws + 32 * N;                     // [N,16]
    unsigned int* part = (unsigned int*)(ws + 48 * N);  // [HB,CNTW] packed u8x4
    int* bp    = (int*)(part + HB * CNTW);       // [HB,N]
    int* rowp1 = bp + HB * N;                    // [N]
    int* lrank = rowp1 + N;                      // [E]
    int* csrc  = lrank + N_EDGES;                // [E]
    int* parts = csrc + N_EDGES;                 // [64]
    int* poff  = parts + 64;                     // [64]
    // total ≈ (48 + 16 + 64 + 1)N + 2E + 128 words ≈ 32 MB

    node1_kernel<<<(N + 63) / 64, 256, 0, stream>>>(
        x, reg_id, dep_id, W_feat, b_feat, reg_emb, dep_emb, W1_l, W1_r, p1, r1);

    hist_lds_kernel<<<HB, 1024, 0, stream>>>(ei, part, lrank);
    scan1_kernel<<<SCAN_NBLK, SCAN_BLK, 0, stream>>>(part, bp, rowp1, parts);
    scan2_kernel<<<1, 64, 0, stream>>>(parts, poff);
    fill_kernel<<<(N_EDGES + 255) / 256, 256, 0, stream>>>(
        ei, rowp1, poff, bp, lrank, csrc);

    gather1_kernel<<<(N * 64 + 255) / 256, 256, 0, stream>>>(
        rowp1, poff, csrc, p1, r1, b1_l, h1);

    gather2_kernel<<<(N * 64 + 255) / 256, 256, 0, stream>>>(
        rowp1, poff, csrc, h1, W2_l, b2_l, W2_r, W_lin, b_lin, out);
}